// Round 16
// baseline (24.755 us; speedup 1.0000x reference)
//
#include <hip/hip_runtime.h>

typedef __attribute__((ext_vector_type(4))) float f32x4;
typedef __attribute__((ext_vector_type(8))) short s16x8;
typedef __attribute__((ext_vector_type(4))) int   i32x4;

constexpr int BATCH = 131072;
constexpr int T = 10;
constexpr int H = 32;

__device__ __forceinline__ unsigned cvt_pk_bf16(float a, float b) {
    unsigned d;
    asm("v_cvt_pk_bf16_f32 %0, %1, %2" : "=v"(d) : "v"(a), "v"(b));
    return d;   // lo16 = bf16(a), hi16 = bf16(b)
}

// hi-only pack: 8 f32 (already in fragment k-order) -> bf16x8 fragment
__device__ __forceinline__ i32x4 pack_hi8(const float (&v)[8]) {
    i32x4 hi;
    #pragma unroll
    for (int p = 0; p < 4; ++p)
        hi[p] = (int)cvt_pk_bf16(v[2*p], v[2*p+1]);
    return hi;
}

__device__ __forceinline__ f32x4 mfma16(i32x4 a, i32x4 b, f32x4 c) {
    return __builtin_amdgcn_mfma_f32_16x16x32_bf16(
        __builtin_bit_cast(s16x8, a), __builtin_bit_cast(s16x8, b), c, 0, 0, 0);
}

__device__ __forceinline__ float fast_tanh(float v) {
    // tanh(v) = 1 - 2/(exp(2v)+1); overflow-safe at both ends
    float e = __expf(2.0f * v);
    return fmaf(-2.0f, __builtin_amdgcn_rcpf(e + 1.0f), 1.0f);
}

// sigma(8g+r') = 4g+r' (r'<4), 16+4g+(r'-4) (r'>=4).
// A'[j][k'] = W_hh[j][sigma(k')]  (pure bf16; residual dropped -> error
// ~2^-9 relative on W, est. <=0.012 final vs 0.0165 threshold),
// B'[k'][m] = h[m][sigma(k')].  D-tile of step t packs directly into step
// t+1's B-fragment (4 cvt_pk), zero cross-lane ops in the loop.
// Output projection rides the MFMA pipe: aout row0 = W_out[sigma(k')].

extern "C" __global__ void __launch_bounds__(256, 4)
rnn_mfma(const float* __restrict__ x,      // [B, T]
         const float* __restrict__ h0,     // [B, H]
         const float* __restrict__ W_ih,   // [H]
         const float* __restrict__ W_hh,   // [H, H] row-major W_hh[j][k]
         const float* __restrict__ b_ih,   // [H]
         const float* __restrict__ b_hh,   // [H]
         const float* __restrict__ W_out,  // [H]
         const float* __restrict__ b_out,  // [1]
         float* __restrict__ out)          // outs [B*T] then hT [B*H]
{
    const int tid  = threadIdx.x;
    const int wave = tid >> 6;
    const int lane = tid & 63;
    const int nl   = lane & 15;            // batch slot m / D col
    const int g    = lane >> 4;
    const int base = blockIdx.x * 128 + wave * 32;   // 2 tiles x 16 rows
    const int m0   = base + nl;
    const int m1   = base + 16 + nl;

    // ---- A' fragments of W_hh (constant, sigma-permuted k', hi-only) ----
    i32x4 a0h, a1h;
    {
        float v[8];
        const float* r0 = W_hh + nl * H;
        float4 u0 = *reinterpret_cast<const float4*>(r0 + 4 * g);
        float4 u1 = *reinterpret_cast<const float4*>(r0 + 16 + 4 * g);
        v[0]=u0.x; v[1]=u0.y; v[2]=u0.z; v[3]=u0.w;
        v[4]=u1.x; v[5]=u1.y; v[6]=u1.z; v[7]=u1.w;
        a0h = pack_hi8(v);
        const float* r1 = W_hh + (nl + 16) * H;
        float4 w0 = *reinterpret_cast<const float4*>(r1 + 4 * g);
        float4 w1 = *reinterpret_cast<const float4*>(r1 + 16 + 4 * g);
        v[0]=w0.x; v[1]=w0.y; v[2]=w0.z; v[3]=w0.w;
        v[4]=w1.x; v[5]=w1.y; v[6]=w1.z; v[7]=w1.w;
        a1h = pack_hi8(v);
    }

    // ---- aout: A row0 = W_out[sigma(k')], other rows zero ----
    i32x4 aout;
    {
        float v[8];
        float4 u0 = *reinterpret_cast<const float4*>(W_out + 4 * g);
        float4 u1 = *reinterpret_cast<const float4*>(W_out + 16 + 4 * g);
        v[0]=u0.x; v[1]=u0.y; v[2]=u0.z; v[3]=u0.w;
        v[4]=u1.x; v[5]=u1.y; v[6]=u1.z; v[7]=u1.w;
        i32x4 tw = pack_hi8(v);
        aout = (nl == 0) ? tw : (i32x4){0, 0, 0, 0};
    }

    // per-lane j-constants for D rows j = 4g+r (tile0) and 16+4g+r (tile1)
    float vb0[4], vw0[4], vb1[4], vw1[4];
    #pragma unroll
    for (int r = 0; r < 4; ++r) {
        const int j0 = 4 * g + r, j1 = j0 + 16;
        vb0[r] = b_ih[j0] + b_hh[j0]; vw0[r] = W_ih[j0];
        vb1[r] = b_ih[j1] + b_hh[j1]; vw1[r] = W_ih[j1];
    }
    const float bo = b_out[0];

    // ---- initial B' fragments from h0 (sigma-permuted columns, hi-only) ----
    i32x4 bh[2];
    #pragma unroll
    for (int u = 0; u < 2; ++u) {
        float v[8];
        const float* hr = h0 + (size_t)((u == 0) ? m0 : m1) * H;
        float4 u0 = *reinterpret_cast<const float4*>(hr + 4 * g);
        float4 u1 = *reinterpret_cast<const float4*>(hr + 16 + 4 * g);
        v[0]=u0.x; v[1]=u0.y; v[2]=u0.z; v[3]=u0.w;
        v[4]=u1.x; v[5]=u1.y; v[6]=u1.z; v[7]=u1.w;
        bh[u] = pack_hi8(v);
    }

    // ---- ALL x upfront: 5 float2 per row (rows are 40B, 8B-aligned) ----
    float xv[2][T];
    {
        const float2* p0 = reinterpret_cast<const float2*>(x + (size_t)m0 * T);
        const float2* p1 = reinterpret_cast<const float2*>(x + (size_t)m1 * T);
        #pragma unroll
        for (int i = 0; i < T / 2; ++i) {
            float2 a = p0[i]; xv[0][2*i] = a.x; xv[0][2*i+1] = a.y;
            float2 b = p1[i]; xv[1][2*i] = b.x; xv[1][2*i+1] = b.y;
        }
    }

    f32x4 d0[2], d1[2];       // tanh'd hidden state (doubles as h storage)

    #pragma unroll
    for (int t = 0; t < T; ++t) {
        const float xt0 = xv[0][t], xt1 = xv[1][t];

        // C init: bias[j] + x[m]*W_ih[j]  (pure f32; x never rounded)
        f32x4 c0[2], c1[2];
        #pragma unroll
        for (int r = 0; r < 4; ++r) {
            c0[0][r] = fmaf(xt0, vw0[r], vb0[r]);
            c1[0][r] = fmaf(xt0, vw1[r], vb1[r]);
            c0[1][r] = fmaf(xt1, vw0[r], vb0[r]);
            c1[1][r] = fmaf(xt1, vw1[r], vb1[r]);
        }

        // D = W_hi · h_hi^T ; two independent chains interleaved, depth-1
        #pragma unroll
        for (int u = 0; u < 2; ++u) { c0[u] = mfma16(a0h, bh[u], c0[u]);
                                      c1[u] = mfma16(a1h, bh[u], c1[u]); }

        #pragma unroll
        for (int u = 0; u < 2; ++u) {
            // tanh in place
            #pragma unroll
            for (int r = 0; r < 4; ++r) {
                d0[u][r] = fast_tanh(c0[u][r]);
                d1[u][r] = fast_tanh(c1[u][r]);
            }
            // D -> B': per-lane hi pack in k'-order
            bh[u] = (i32x4){(int)cvt_pk_bf16(d0[u][0], d0[u][1]),
                            (int)cvt_pk_bf16(d0[u][2], d0[u][3]),
                            (int)cvt_pk_bf16(d1[u][0], d1[u][1]),
                            (int)cvt_pk_bf16(d1[u][2], d1[u][3])};
            // o = W_out · h_new via MFMA row0 (off the critical path)
            f32x4 oacc = {0.0f, 0.0f, 0.0f, 0.0f};
            oacc = mfma16(aout, bh[u], oacc);
            if (g == 0) out[(size_t)(base + u * 16 + nl) * T + t] = oacc[0] + bo;
        }
    }

    // hT: h[m][j]; d0 rows j=4g..4g+3, d1 rows 16+4g..16+4g+3 per tile
    #pragma unroll
    for (int u = 0; u < 2; ++u) {
        float* hb = out + (size_t)BATCH * T + (size_t)(base + u * 16 + nl) * H;
        float4 s0, s1;
        s0.x = d0[u][0]; s0.y = d0[u][1]; s0.z = d0[u][2]; s0.w = d0[u][3];
        s1.x = d1[u][0]; s1.y = d1[u][1]; s1.z = d1[u][2]; s1.w = d1[u][3];
        *reinterpret_cast<float4*>(hb + 4 * g)      = s0;
        *reinterpret_cast<float4*>(hb + 16 + 4 * g) = s1;
    }
}

extern "C" void kernel_launch(void* const* d_in, const int* in_sizes, int n_in,
                              void* d_out, int out_size, void* d_ws, size_t ws_size,
                              hipStream_t stream) {
    const float* x     = (const float*)d_in[0];
    const float* h0    = (const float*)d_in[1];
    const float* W_ih  = (const float*)d_in[2];
    const float* W_hh  = (const float*)d_in[3];
    const float* b_ih  = (const float*)d_in[4];
    const float* b_hh  = (const float*)d_in[5];
    const float* W_out = (const float*)d_in[6];
    const float* b_out = (const float*)d_in[7];
    float* out = (float*)d_out;

    rnn_mfma<<<BATCH / 128, 256, 0, stream>>>(
        x, h0, W_ih, W_hh, b_ih, b_hh, W_out, b_out, out);
}

// Round 19
// 24.208 us; speedup vs baseline: 1.0226x; 1.0226x over previous
//
#include <hip/hip_runtime.h>

typedef __attribute__((ext_vector_type(4))) float f32x4;
typedef __attribute__((ext_vector_type(8))) short s16x8;
typedef __attribute__((ext_vector_type(4))) int   i32x4;

constexpr int BATCH = 131072;
constexpr int T = 10;
constexpr int H = 32;

__device__ __forceinline__ unsigned cvt_pk_bf16(float a, float b) {
    unsigned d;
    asm("v_cvt_pk_bf16_f32 %0, %1, %2" : "=v"(d) : "v"(a), "v"(b));
    return d;   // lo16 = bf16(a), hi16 = bf16(b)
}

// 8 f32 (in fragment k-order) -> bf16x8 hi fragment + lo (residual) fragment
__device__ __forceinline__ void pack_hilo8(const float (&v)[8], i32x4& hi, i32x4& lo) {
    #pragma unroll
    for (int p = 0; p < 4; ++p) {
        unsigned hb = cvt_pk_bf16(v[2*p], v[2*p+1]);
        float f0 = __builtin_bit_cast(float, hb << 16);
        float f1 = __builtin_bit_cast(float, hb & 0xFFFF0000u);
        hi[p] = (int)hb;
        lo[p] = (int)cvt_pk_bf16(v[2*p] - f0, v[2*p+1] - f1);
    }
}

// hi-only pack
__device__ __forceinline__ i32x4 pack_hi8(const float (&v)[8]) {
    i32x4 hi;
    #pragma unroll
    for (int p = 0; p < 4; ++p)
        hi[p] = (int)cvt_pk_bf16(v[2*p], v[2*p+1]);
    return hi;
}

__device__ __forceinline__ f32x4 mfma16(i32x4 a, i32x4 b, f32x4 c) {
    return __builtin_amdgcn_mfma_f32_16x16x32_bf16(
        __builtin_bit_cast(s16x8, a), __builtin_bit_cast(s16x8, b), c, 0, 0, 0);
}

__device__ __forceinline__ float fast_tanh(float v) {
    // tanh(v) = 1 - 2/(exp(2v)+1); overflow-safe at both ends.
    // __expf ONLY — __builtin_amdgcn_exp2f mis-executed 2/2 (R15, R17).
    float e = __expf(2.0f * v);
    return fmaf(-2.0f, __builtin_amdgcn_rcpf(e + 1.0f), 1.0f);
}

// sigma(8g+r') = 4g+r' (r'<4), 16+4g+(r'-4) (r'>=4).
// A'[j][k'] = W_hh[j][sigma(k')] (split bf16 hi+lo; W fp32-accurate),
// B'[k'][m] = h[m][sigma(k')].  D-tile of step t packs directly into step
// t+1's B-fragment (4 cvt_pk), zero cross-lane ops in the loop.
// Output projection rides the MFMA pipe: aout row0 = W_out[sigma(k')];
// o stores in-loop under g==0 (register-epilogue variant miscompiled, R18).

extern "C" __global__ void __launch_bounds__(256, 4)
rnn_mfma(const float* __restrict__ x,      // [B, T]
         const float* __restrict__ h0,     // [B, H]
         const float* __restrict__ W_ih,   // [H]
         const float* __restrict__ W_hh,   // [H, H] row-major W_hh[j][k]
         const float* __restrict__ b_ih,   // [H]
         const float* __restrict__ b_hh,   // [H]
         const float* __restrict__ W_out,  // [H]
         const float* __restrict__ b_out,  // [1]
         float* __restrict__ out)          // outs [B*T] then hT [B*H]
{
    const int tid  = threadIdx.x;
    const int wave = tid >> 6;
    const int lane = tid & 63;
    const int nl   = lane & 15;            // batch slot m / D col
    const int g    = lane >> 4;
    const int base = blockIdx.x * 128 + wave * 32;   // 2 tiles x 16 rows
    const int m0   = base + nl;
    const int m1   = base + 16 + nl;

    // ---- A' fragments of W_hh (constant, sigma-permuted k') ----
    i32x4 a0h, a0l, a1h, a1l;
    {
        float v[8];
        const float* r0 = W_hh + nl * H;
        float4 u0 = *reinterpret_cast<const float4*>(r0 + 4 * g);
        float4 u1 = *reinterpret_cast<const float4*>(r0 + 16 + 4 * g);
        v[0]=u0.x; v[1]=u0.y; v[2]=u0.z; v[3]=u0.w;
        v[4]=u1.x; v[5]=u1.y; v[6]=u1.z; v[7]=u1.w;
        pack_hilo8(v, a0h, a0l);
        const float* r1 = W_hh + (nl + 16) * H;
        float4 w0 = *reinterpret_cast<const float4*>(r1 + 4 * g);
        float4 w1 = *reinterpret_cast<const float4*>(r1 + 16 + 4 * g);
        v[0]=w0.x; v[1]=w0.y; v[2]=w0.z; v[3]=w0.w;
        v[4]=w1.x; v[5]=w1.y; v[6]=w1.z; v[7]=w1.w;
        pack_hilo8(v, a1h, a1l);
    }

    // ---- aout: A row0 = W_out[sigma(k')], other rows zero ----
    i32x4 aout;
    {
        float v[8];
        float4 u0 = *reinterpret_cast<const float4*>(W_out + 4 * g);
        float4 u1 = *reinterpret_cast<const float4*>(W_out + 16 + 4 * g);
        v[0]=u0.x; v[1]=u0.y; v[2]=u0.z; v[3]=u0.w;
        v[4]=u1.x; v[5]=u1.y; v[6]=u1.z; v[7]=u1.w;
        i32x4 tw = pack_hi8(v);
        aout = (nl == 0) ? tw : (i32x4){0, 0, 0, 0};
    }

    // per-lane j-constants for D rows j = 4g+r (tile0) and 16+4g+r (tile1)
    float vb0[4], vw0[4], vb1[4], vw1[4];
    #pragma unroll
    for (int r = 0; r < 4; ++r) {
        const int j0 = 4 * g + r, j1 = j0 + 16;
        vb0[r] = b_ih[j0] + b_hh[j0]; vw0[r] = W_ih[j0];
        vb1[r] = b_ih[j1] + b_hh[j1]; vw1[r] = W_ih[j1];
    }
    const float bo = b_out[0];

    // ---- initial B' fragments from h0 (sigma-permuted columns, hi-only) ----
    i32x4 bh[2];
    #pragma unroll
    for (int u = 0; u < 2; ++u) {
        float v[8];
        const float* hr = h0 + (size_t)((u == 0) ? m0 : m1) * H;
        float4 u0 = *reinterpret_cast<const float4*>(hr + 4 * g);
        float4 u1 = *reinterpret_cast<const float4*>(hr + 16 + 4 * g);
        v[0]=u0.x; v[1]=u0.y; v[2]=u0.z; v[3]=u0.w;
        v[4]=u1.x; v[5]=u1.y; v[6]=u1.z; v[7]=u1.w;
        bh[u] = pack_hi8(v);
    }

    // ---- ALL x upfront: 5 float2 per row (rows are 40B, 8B-aligned) ----
    float xv[2][T];
    {
        const float2* p0 = reinterpret_cast<const float2*>(x + (size_t)m0 * T);
        const float2* p1 = reinterpret_cast<const float2*>(x + (size_t)m1 * T);
        #pragma unroll
        for (int i = 0; i < T / 2; ++i) {
            float2 a = p0[i]; xv[0][2*i] = a.x; xv[0][2*i+1] = a.y;
            float2 b = p1[i]; xv[1][2*i] = b.x; xv[1][2*i+1] = b.y;
        }
    }

    f32x4 d0[2], d1[2];       // tanh'd hidden state (doubles as h storage)

    #pragma unroll
    for (int t = 0; t < T; ++t) {
        const float xt0 = xv[0][t], xt1 = xv[1][t];

        // C init: bias[j] + x[m]*W_ih[j]  (pure f32; x never rounded)
        f32x4 c0[2], c1[2];
        #pragma unroll
        for (int r = 0; r < 4; ++r) {
            c0[0][r] = fmaf(xt0, vw0[r], vb0[r]);
            c1[0][r] = fmaf(xt0, vw1[r], vb1[r]);
            c0[1][r] = fmaf(xt1, vw0[r], vb0[r]);
            c1[1][r] = fmaf(xt1, vw1[r], vb1[r]);
        }

        // D = (W_hi + W_lo) · h_hi^T ; two independent chains interleaved
        #pragma unroll
        for (int u = 0; u < 2; ++u) { c0[u] = mfma16(a0h, bh[u], c0[u]);
                                      c1[u] = mfma16(a1h, bh[u], c1[u]); }
        #pragma unroll
        for (int u = 0; u < 2; ++u) { c0[u] = mfma16(a0l, bh[u], c0[u]);
                                      c1[u] = mfma16(a1l, bh[u], c1[u]); }

        #pragma unroll
        for (int u = 0; u < 2; ++u) {
            // tanh in place
            #pragma unroll
            for (int r = 0; r < 4; ++r) {
                d0[u][r] = fast_tanh(c0[u][r]);
                d1[u][r] = fast_tanh(c1[u][r]);
            }
            // D -> B': per-lane hi pack in k'-order
            bh[u] = (i32x4){(int)cvt_pk_bf16(d0[u][0], d0[u][1]),
                            (int)cvt_pk_bf16(d0[u][2], d0[u][3]),
                            (int)cvt_pk_bf16(d1[u][0], d1[u][1]),
                            (int)cvt_pk_bf16(d1[u][2], d1[u][3])};
            // o = W_out · h_new via MFMA row0 (off the critical path)
            f32x4 oacc = {0.0f, 0.0f, 0.0f, 0.0f};
            oacc = mfma16(aout, bh[u], oacc);
            if (g == 0) out[(size_t)(base + u * 16 + nl) * T + t] = oacc[0] + bo;
        }
    }

    // hT: h[m][j]; d0 rows j=4g..4g+3, d1 rows 16+4g..16+4g+3 per tile
    #pragma unroll
    for (int u = 0; u < 2; ++u) {
        float* hb = out + (size_t)BATCH * T + (size_t)(base + u * 16 + nl) * H;
        float4 s0, s1;
        s0.x = d0[u][0]; s0.y = d0[u][1]; s0.z = d0[u][2]; s0.w = d0[u][3];
        s1.x = d1[u][0]; s1.y = d1[u][1]; s1.z = d1[u][2]; s1.w = d1[u][3];
        *reinterpret_cast<float4*>(hb + 4 * g)      = s0;
        *reinterpret_cast<float4*>(hb + 16 + 4 * g) = s1;
    }
}

extern "C" void kernel_launch(void* const* d_in, const int* in_sizes, int n_in,
                              void* d_out, int out_size, void* d_ws, size_t ws_size,
                              hipStream_t stream) {
    const float* x     = (const float*)d_in[0];
    const float* h0    = (const float*)d_in[1];
    const float* W_ih  = (const float*)d_in[2];
    const float* W_hh  = (const float*)d_in[3];
    const float* b_ih  = (const float*)d_in[4];
    const float* b_hh  = (const float*)d_in[5];
    const float* W_out = (const float*)d_in[6];
    const float* b_out = (const float*)d_in[7];
    float* out = (float*)d_out;

    rnn_mfma<<<BATCH / 128, 256, 0, stream>>>(
        x, h0, W_ih, W_hh, b_ih, b_hh, W_out, b_out, out);
}